// Round 11
// baseline (3928.331 us; speedup 1.0000x reference)
//
#include <hip/hip_runtime.h>
#include <hip/hip_bf16.h>
#include <math.h>

#define NN_ 65536
#define NE_ 131072
#define B_  32
#define T_  4096
#define D_  8          // GRU X3 ring-prefetch depth (steps)

typedef __fp16 f16x2 __attribute__((ext_vector_type(2)));
typedef unsigned int u32;

__device__ __forceinline__ float gelu_f(float x){
    return 0.5f*x*(1.0f + erff(x*0.70710678118654752f));
}

__device__ __forceinline__ unsigned enc_f(float f){
    unsigned b = __float_as_uint(f);
    return (b & 0x80000000u) ? ~b : (b | 0x80000000u);
}
__device__ __forceinline__ float dec_f(unsigned u){
    return (u & 0x80000000u) ? __uint_as_float(u ^ 0x80000000u) : __uint_as_float(~u);
}

__device__ __forceinline__ float rdlane(float v, int l){
    return __int_as_float(__builtin_amdgcn_readlane(__float_as_int(v), l));
}

__device__ __forceinline__ float dot2(f16x2 a, f16x2 b, float c){
#if __has_builtin(__builtin_amdgcn_fdot2)
    return __builtin_amdgcn_fdot2(a, b, c, false);
#else
    return c + (float)a.x*(float)b.x + (float)a.y*(float)b.y;
#endif
}

// async global->LDS: lane i loads *(g_perlane) -> lds_base + i*4
__device__ __forceinline__ void gload_lds4(const float* g, float* l, int lane){
#if __has_builtin(__builtin_amdgcn_global_load_lds)
    __builtin_amdgcn_global_load_lds((const __attribute__((address_space(1))) u32*)g,
                                     (__attribute__((address_space(3))) u32*)l, 4, 0, 0);
#else
    l[lane] = *g;
#endif
}

// ---------------- embed concat ----------------
__global__ void k_embed(const float* __restrict__ x, const int* __restrict__ nidx,
                        const float* __restrict__ emb, float* __restrict__ h64){
    int gid = blockIdx.x*256 + threadIdx.x;
    int n = gid >> 6, c = gid & 63;
    float v = (c < 32) ? x[(size_t)n*32 + c] : emb[(size_t)nidx[n]*32 + (c-32)];
    h64[gid] = v;
}

// ---------------- node GEMM: C[M,128] = A[M,K] @ W[K,128] ----------------
template<int K>
__global__ void k_gemm_node(const float* __restrict__ A, const float* __restrict__ W,
                            float* __restrict__ C){
    int lane = threadIdx.x & 63;
    int wy = threadIdx.x >> 6;
    int r0 = blockIdx.x*16 + wy*4;
    const float* a0 = A + (size_t)r0*K;
    float acc0[4] = {0,0,0,0}, acc1[4] = {0,0,0,0};
    #pragma unroll 4
    for(int k=0;k<K;k+=4){
        float4 av[4];
        #pragma unroll
        for(int i=0;i<4;i++) av[i] = *(const float4*)(a0 + (size_t)i*K + k);
        #pragma unroll
        for(int kk=0;kk<4;kk++){
            float w0 = W[(size_t)(k+kk)*128 + lane];
            float w1 = W[(size_t)(k+kk)*128 + 64 + lane];
            #pragma unroll
            for(int i=0;i<4;i++){
                float a = ((const float*)&av[i])[kk];
                acc0[i] += a*w0;
                acc1[i] += a*w1;
            }
        }
    }
    #pragma unroll
    for(int i=0;i<4;i++){
        C[(size_t)(r0+i)*128 + lane]      = acc0[i];
        C[(size_t)(r0+i)*128 + 64 + lane] = acc1[i];
    }
}

// ---------------- per-row dots (+ zero-init of ssum/menc) ---------------------
__global__ void k_rowdots(const float* __restrict__ hW, const float* __restrict__ as_,
                          const float* __restrict__ ad_, float* __restrict__ ssrc,
                          float* __restrict__ sdst, float* __restrict__ ssum,
                          unsigned* __restrict__ menc){
    int lane = threadIdx.x & 63;
    int row = blockIdx.x*4 + (threadIdx.x >> 6);
    const float* hp = hW + (size_t)row*128;
    float h0 = hp[lane], h1 = hp[lane+64];
    float d0 = h0*as_[lane] + h1*as_[lane+64];
    float d1 = h0*ad_[lane] + h1*ad_[lane+64];
    #pragma unroll
    for(int off=32; off; off>>=1){
        d0 += __shfl_xor(d0, off);
        d1 += __shfl_xor(d1, off);
    }
    if(lane==0){
        ssrc[row] = d0; sdst[row] = d1;
        ssum[row] = 0.f; menc[row] = 0u;   // 0 < enc_f(any finite v)
    }
}

// ---------------- edge pass 1 ----------------
__global__ void k_edge1(const int* __restrict__ src, const int* __restrict__ dst,
                        const float* __restrict__ ssrc, const float* __restrict__ sdst,
                        float* __restrict__ ebuf, unsigned* __restrict__ menc){
    int e = blockIdx.x*256 + threadIdx.x;   // e < NE_+NN_
    int s, d;
    if(e < NE_){ s = src[e]; d = dst[e]; } else { s = d = e - NE_; }
    float v = ssrc[s] + sdst[d];
    v = (v > 0.f) ? v : 0.2f*v;
    ebuf[e] = v;
    atomicMax(&menc[d], enc_f(v));
}

// ---------------- edge pass 2 ----------------
__global__ void k_edge2(const int* __restrict__ dst, const unsigned* __restrict__ menc,
                        float* __restrict__ ebuf, float* __restrict__ ssum){
    int e = blockIdx.x*256 + threadIdx.x;
    int d = (e < NE_) ? dst[e] : (e - NE_);
    float m = dec_f(menc[d]);
    float ex = __expf(ebuf[e] - m);
    ebuf[e] = ex;
    atomicAdd(&ssum[d], ex);
}

// ---------------- edge pass 3 (LDS-staged per graph) + alpha + bias + gelu ----
// grid (32 graphs, 8 ch-groups of 16); block 256. agg[2048][16] = 128KB LDS.
// 16 consecutive channels/lane-group -> 64B contiguous gathers; 4-deep batch
// keeps gather latency pipelined at 1 block/CU.
__global__ void __launch_bounds__(256) k_edge3_lds(
        const int* __restrict__ src, const int* __restrict__ dst,
        const float* __restrict__ ebuf, const float* __restrict__ ssum,
        const float* __restrict__ hW, const float* __restrict__ bias,
        float* __restrict__ hAgg){
    __shared__ float agg[2048][16];
    int g  = blockIdx.x;
    int c0 = blockIdx.y << 4;
    int t  = threadIdx.x;
    int cc = t & 15;
    int elane = t >> 4;              // 0..15 (16 edges per sub-iter)

    for(int idx = t; idx < 2048*16; idx += 256)
        ((float*)agg)[idx] = 0.f;
    __syncthreads();

    const int gbase_e = g << 12;     // g*4096 edges
    const int gbase_n = g << 11;     // g*2048 nodes
    for(int i0 = 0; i0 < 384; i0 += 4){
        int   s_[4], dl_[4];
        float a_[4];
        #pragma unroll
        for(int u=0;u<4;u++){
            int eg = (i0+u)*16 + elane;   // 0..6143
            if(eg < 4096){
                int e = gbase_e + eg;
                s_[u]  = src[e];
                int d  = dst[e];
                dl_[u] = d - gbase_n;
                a_[u]  = ebuf[e] / ssum[d];
            } else {
                int nl = eg - 4096;
                s_[u]  = gbase_n + nl;
                dl_[u] = nl;
                a_[u]  = ebuf[NE_ + gbase_n + nl] / ssum[gbase_n + nl];
            }
        }
        #pragma unroll
        for(int u=0;u<4;u++){
            float v = hW[(size_t)s_[u]*128 + c0 + cc] * a_[u];
            atomicAdd(&agg[dl_[u]][cc], v);
        }
    }
    __syncthreads();

    for(int idx = t; idx < 2048*16; idx += 256){
        int nl = idx >> 4;
        int ch = c0 + (idx & 15);
        hAgg[((size_t)(gbase_n + nl))*128 + ch] = gelu_f(agg[nl][idx & 15] + bias[ch]);
    }
}

// ------- fused edge-FC + GRU input projection -------
__global__ void k_ef_x3(const float* __restrict__ h3, const int* __restrict__ src,
                        const int* __restrict__ dst, const float* __restrict__ fcW,
                        const float* __restrict__ fcb,
                        const float* __restrict__ Wz, const float* __restrict__ Wr,
                        const float* __restrict__ Wh, const float* __restrict__ bz,
                        const float* __restrict__ br, const float* __restrict__ bh,
                        float* __restrict__ X3){
    __shared__ float efs[16][128];
    int lane = threadIdx.x & 63;
    int wy = threadIdx.x >> 6;
    int e0 = blockIdx.x*16 + wy*4;

    {
        float acc0[4] = {0,0,0,0}, acc1[4] = {0,0,0,0};
        #pragma unroll
        for(int half=0; half<2; half++){
            const float* rowp[4];
            #pragma unroll
            for(int i=0;i<4;i++){
                int n = (half==0) ? src[e0+i] : dst[e0+i];
                rowp[i] = h3 + (size_t)n*128;
            }
            #pragma unroll 2
            for(int k=0;k<128;k+=4){
                float4 av[4];
                #pragma unroll
                for(int i=0;i<4;i++) av[i] = *(const float4*)(rowp[i] + k);
                #pragma unroll
                for(int kk=0;kk<4;kk++){
                    int kw = half*128 + k + kk;
                    float w0 = fcW[(size_t)kw*128 + lane];
                    float w1 = fcW[(size_t)kw*128 + 64 + lane];
                    #pragma unroll
                    for(int i=0;i<4;i++){
                        float a = ((const float*)&av[i])[kk];
                        acc0[i] += a*w0;
                        acc1[i] += a*w1;
                    }
                }
            }
        }
        float b0 = fcb[lane], b1 = fcb[64+lane];
        #pragma unroll
        for(int i=0;i<4;i++){
            efs[wy*4+i][lane]      = gelu_f(acc0[i] + b0);
            efs[wy*4+i][64 + lane] = gelu_f(acc1[i] + b1);
        }
    }
    __syncthreads();
    {
        float accz[4] = {0,0,0,0}, accr[4] = {0,0,0,0}, acch[4] = {0,0,0,0};
        #pragma unroll 2
        for(int k=0;k<128;k+=4){
            #pragma unroll
            for(int kk=0;kk<4;kk++){
                float w0 = Wz[(size_t)(k+kk)*64 + lane];
                float w1 = Wr[(size_t)(k+kk)*64 + lane];
                float w2 = Wh[(size_t)(k+kk)*64 + lane];
                #pragma unroll
                for(int i=0;i<4;i++){
                    float a = efs[wy*4+i][k+kk];
                    accz[i] += a*w0;
                    accr[i] += a*w1;
                    acch[i] += a*w2;
                }
            }
        }
        float b0 = bz[lane], b1 = br[lane], b2 = bh[lane];
        #pragma unroll
        for(int i=0;i<4;i++){
            int e = e0 + i;
            int bb = e >> 12;
            int t  = e & 4095;
            float* o = X3 + ((size_t)t*32 + bb)*192;
            o[lane]       = accz[i] + b0;
            o[64 + lane]  = accr[i] + b1;
            o[128 + lane] = acch[i] + b2;
        }
    }
}

// ---------------- GRU: 4 waves/batch, f16x2 k-split + D=8 LDS ring ------------
// Wave w owns k in [16w,16w+16). h/rh pair packs built by DIRECT v_readlane +
// cvt_pkrtz (pure VALU) — R10's __shfl_xor pre-pack was 2 DS-latency hits/step.
__global__ void __launch_bounds__(256) k_gru(const float* __restrict__ X3,
                       const float* __restrict__ Wz, const float* __restrict__ Wr,
                       const float* __restrict__ Wh, float* __restrict__ out){
    __shared__ float  ring[D_][192];
    __shared__ float2 P1[4][64];
    __shared__ float  P2[4][64];
    int b = blockIdx.x;
    int j = threadIdx.x & 63;
    int w = __builtin_amdgcn_readfirstlane(threadIdx.x >> 6);  // 0..3
    int kbase = w << 4;

    // packed hidden-part weight columns for this wave's k-range
    f16x2 wzp[8], wrp[8], whp[8];
    #pragma unroll
    for(int i=0;i<8;i++){
        int r0 = 128 + kbase + 2*i;
        wzp[i] = __builtin_amdgcn_cvt_pkrtz(Wz[(size_t)r0*64 + j], Wz[(size_t)(r0+1)*64 + j]);
        wrp[i] = __builtin_amdgcn_cvt_pkrtz(Wr[(size_t)r0*64 + j], Wr[(size_t)(r0+1)*64 + j]);
        whp[i] = __builtin_amdgcn_cvt_pkrtz(Wh[(size_t)r0*64 + j], Wh[(size_t)(r0+1)*64 + j]);
    }

    // prologue: wave 0 fills ring slots 0..D-1 (3 loads per step)
    if(w == 0){
        for(int s=0;s<D_;s++){
            const float* gp = X3 + ((size_t)s*32 + b)*192 + j;
            gload_lds4(gp,       &ring[s][0],   j);
            gload_lds4(gp + 64,  &ring[s][64],  j);
            gload_lds4(gp + 128, &ring[s][128], j);
        }
        asm volatile("s_waitcnt vmcnt(21)" ::: "memory");   // slot 0 ready
        __builtin_amdgcn_sched_barrier(0);
    }
    __builtin_amdgcn_s_barrier();

    float h = 0.f;
    for(int step=0; step<T_; step++){
        int sl = step & (D_-1);
        float xz = ring[sl][j], xr = ring[sl][64+j], xh = ring[sl][128+j];

        // phase 1: partial z/r over k in [kbase, kbase+16)
        float az0=0.f, az1=0.f, ar0=0.f, ar1=0.f;
        #pragma unroll
        for(int i=0;i<8;i+=2){
            f16x2 h0 = __builtin_amdgcn_cvt_pkrtz(rdlane(h, kbase+2*i),
                                                  rdlane(h, kbase+2*i+1));
            f16x2 h1 = __builtin_amdgcn_cvt_pkrtz(rdlane(h, kbase+2*i+2),
                                                  rdlane(h, kbase+2*i+3));
            az0 = dot2(h0, wzp[i],   az0); ar0 = dot2(h0, wrp[i],   ar0);
            az1 = dot2(h1, wzp[i+1], az1); ar1 = dot2(h1, wrp[i+1], ar1);
        }
        P1[w][j] = make_float2(az0+az1, ar0+ar1);
        asm volatile("s_waitcnt lgkmcnt(0)" ::: "memory");  // P1 visible; ring reads done
        __builtin_amdgcn_s_barrier();                       // barrier 1

        // slot sl free everywhere: wave 0 prefetches step+D into it
        if(w == 0){
            int ps = (step + D_ < T_) ? (step + D_) : (T_-1);
            const float* gp = X3 + ((size_t)ps*32 + b)*192 + j;
            gload_lds4(gp,       &ring[sl][0],   j);
            gload_lds4(gp + 64,  &ring[sl][64],  j);
            gload_lds4(gp + 128, &ring[sl][128], j);
        }

        float2 q0 = P1[0][j], q1 = P1[1][j], q2 = P1[2][j], q3 = P1[3][j];
        float sz = xz + ((q0.x+q1.x)+(q2.x+q3.x));
        float sr = xr + ((q0.y+q1.y)+(q2.y+q3.y));
        float z = __builtin_amdgcn_rcpf(1.f + __expf(-sz));
        float r = __builtin_amdgcn_rcpf(1.f + __expf(-sr));
        float rh = r*h;

        // phase 2: partial ht over k-range (direct readlane packs of rh)
        float ah0=0.f, ah1=0.f;
        #pragma unroll
        for(int i=0;i<8;i+=2){
            f16x2 r0 = __builtin_amdgcn_cvt_pkrtz(rdlane(rh, kbase+2*i),
                                                  rdlane(rh, kbase+2*i+1));
            f16x2 r1 = __builtin_amdgcn_cvt_pkrtz(rdlane(rh, kbase+2*i+2),
                                                  rdlane(rh, kbase+2*i+3));
            ah0 = dot2(r0, whp[i],   ah0);
            ah1 = dot2(r1, whp[i+1], ah1);
        }
        P2[w][j] = ah0 + ah1;
        if(w == 0){
            asm volatile("s_waitcnt vmcnt(21)" ::: "memory");  // next slot ready
        }
        asm volatile("s_waitcnt lgkmcnt(0)" ::: "memory");     // P2 visible
        __builtin_amdgcn_s_barrier();                          // barrier 2

        float s2 = xh + ((P2[0][j]+P2[1][j]) + (P2[2][j]+P2[3][j]));
        float ht = fmaxf(s2, 0.01f*s2);
        h = fmaf(z, ht - h, h);    // identical in all waves -> h stays replicated
    }
    if(w == 0) out[(size_t)b*64 + j] = h;
}

extern "C" void kernel_launch(void* const* d_in, const int* in_sizes, int n_in,
                              void* d_out, int out_size, void* d_ws, size_t ws_size,
                              hipStream_t stream) {
    const float* x    = (const float*)d_in[0];
    const int*   nidx = (const int*)d_in[1];
    const int*   src  = (const int*)d_in[2];
    const int*   dst  = src + NE_;
    const float* emb  = (const float*)d_in[3];
    const float* W1 = (const float*)d_in[4];
    const float* a1s = (const float*)d_in[5];
    const float* a1d = (const float*)d_in[6];
    const float* b1 = (const float*)d_in[7];
    const float* W2 = (const float*)d_in[8];
    const float* a2s = (const float*)d_in[9];
    const float* a2d = (const float*)d_in[10];
    const float* b2 = (const float*)d_in[11];
    const float* W3 = (const float*)d_in[12];
    const float* a3s = (const float*)d_in[13];
    const float* a3d = (const float*)d_in[14];
    const float* b3 = (const float*)d_in[15];
    const float* fcW = (const float*)d_in[16];
    const float* fcb = (const float*)d_in[17];
    const float* Wz = (const float*)d_in[18];
    const float* bz = (const float*)d_in[19];
    const float* Wr = (const float*)d_in[20];
    const float* br = (const float*)d_in[21];
    const float* Wh = (const float*)d_in[22];
    const float* bh = (const float*)d_in[23];
    float* out = (float*)d_out;

    float* ws = (float*)d_ws;
    float* hAgg = ws;                          // NN*128
    float* X3   = hAgg + (size_t)NN_*128;      // NE*192
    float* bufA = X3;                          // NN*128   (alias)
    float* h64  = bufA + (size_t)NN_*128;      // NN*64    (alias)
    float* ssrc = h64  + (size_t)NN_*64;       // NN       (alias)
    float* sdst = ssrc + NN_;                  // NN
    float* ssum = sdst + NN_;                  // NN
    unsigned* menc = (unsigned*)(ssum + NN_);  // NN
    float* ebuf = (float*)menc + NN_;          // NE+NN

    const int EP = NE_ + NN_;

    k_embed<<<NN_*64/256, 256, 0, stream>>>(x, nidx, emb, h64);

    const float* Ws[3]  = {W1, W2, W3};
    const float* as_[3] = {a1s, a2s, a3s};
    const float* ad_[3] = {a1d, a2d, a3d};
    const float* bs[3]  = {b1, b2, b3};

    for(int l=0; l<3; l++){
        if(l == 0)
            k_gemm_node<64><<<NN_/16, 256, 0, stream>>>(h64, Ws[l], bufA);
        else
            k_gemm_node<128><<<NN_/16, 256, 0, stream>>>(hAgg, Ws[l], bufA);
        k_rowdots<<<NN_/4, 256, 0, stream>>>(bufA, as_[l], ad_[l], ssrc, sdst, ssum, menc);
        k_edge1<<<EP/256, 256, 0, stream>>>(src, dst, ssrc, sdst, ebuf, menc);
        k_edge2<<<EP/256, 256, 0, stream>>>(dst, menc, ebuf, ssum);
        k_edge3_lds<<<dim3(B_, 8), 256, 0, stream>>>(src, dst, ebuf, ssum, bufA, bs[l], hAgg);
    }

    k_ef_x3<<<NE_/16, 256, 0, stream>>>(hAgg, src, dst, fcW, fcb,
                                        Wz, Wr, Wh, bz, br, bh, X3);
    k_gru<<<B_, 256, 0, stream>>>(X3, Wz, Wr, Wh, out);
}

// Round 12
// 3405.033 us; speedup vs baseline: 1.1537x; 1.1537x over previous
//
#include <hip/hip_runtime.h>
#include <hip/hip_bf16.h>
#include <math.h>

#define NN_ 65536
#define NE_ 131072
#define B_  32
#define T_  4096
#define D_  8          // GRU X3 ring-prefetch depth (steps)

typedef __fp16 f16x2 __attribute__((ext_vector_type(2)));
typedef unsigned int u32;

__device__ __forceinline__ float gelu_f(float x){
    return 0.5f*x*(1.0f + erff(x*0.70710678118654752f));
}

__device__ __forceinline__ unsigned enc_f(float f){
    unsigned b = __float_as_uint(f);
    return (b & 0x80000000u) ? ~b : (b | 0x80000000u);
}
__device__ __forceinline__ float dec_f(unsigned u){
    return (u & 0x80000000u) ? __uint_as_float(u ^ 0x80000000u) : __uint_as_float(~u);
}

__device__ __forceinline__ int h2i(f16x2 h){ union{int i; f16x2 h;} u; u.h=h; return u.i; }
__device__ __forceinline__ f16x2 i2h(int i){ union{int i; f16x2 h;} u; u.i=i; return u.h; }

__device__ __forceinline__ float dot2(f16x2 a, f16x2 b, float c){
#if __has_builtin(__builtin_amdgcn_fdot2)
    return __builtin_amdgcn_fdot2(a, b, c, false);
#else
    return c + (float)a.x*(float)b.x + (float)a.y*(float)b.y;
#endif
}

// async global->LDS: lane i loads *(g_perlane) -> lds_base + i*4
__device__ __forceinline__ void gload_lds4(const float* g, float* l, int lane){
#if __has_builtin(__builtin_amdgcn_global_load_lds)
    __builtin_amdgcn_global_load_lds((const __attribute__((address_space(1))) u32*)g,
                                     (__attribute__((address_space(3))) u32*)l, 4, 0, 0);
#else
    l[lane] = *g;
#endif
}

// ---------------- embed concat ----------------
__global__ void k_embed(const float* __restrict__ x, const int* __restrict__ nidx,
                        const float* __restrict__ emb, float* __restrict__ h64){
    int gid = blockIdx.x*256 + threadIdx.x;
    int n = gid >> 6, c = gid & 63;
    float v = (c < 32) ? x[(size_t)n*32 + c] : emb[(size_t)nidx[n]*32 + (c-32)];
    h64[gid] = v;
}

// ---------------- node GEMM: C[M,128] = A[M,K] @ W[K,128] ----------------
template<int K>
__global__ void k_gemm_node(const float* __restrict__ A, const float* __restrict__ W,
                            float* __restrict__ C){
    int lane = threadIdx.x & 63;
    int wy = threadIdx.x >> 6;
    int r0 = blockIdx.x*16 + wy*4;
    const float* a0 = A + (size_t)r0*K;
    float acc0[4] = {0,0,0,0}, acc1[4] = {0,0,0,0};
    #pragma unroll 4
    for(int k=0;k<K;k+=4){
        float4 av[4];
        #pragma unroll
        for(int i=0;i<4;i++) av[i] = *(const float4*)(a0 + (size_t)i*K + k);
        #pragma unroll
        for(int kk=0;kk<4;kk++){
            float w0 = W[(size_t)(k+kk)*128 + lane];
            float w1 = W[(size_t)(k+kk)*128 + 64 + lane];
            #pragma unroll
            for(int i=0;i<4;i++){
                float a = ((const float*)&av[i])[kk];
                acc0[i] += a*w0;
                acc1[i] += a*w1;
            }
        }
    }
    #pragma unroll
    for(int i=0;i<4;i++){
        C[(size_t)(r0+i)*128 + lane]      = acc0[i];
        C[(size_t)(r0+i)*128 + 64 + lane] = acc1[i];
    }
}

// ---------------- per-row dots (+ zero-init of ssum/menc) ---------------------
__global__ void k_rowdots(const float* __restrict__ hW, const float* __restrict__ as_,
                          const float* __restrict__ ad_, float* __restrict__ ssrc,
                          float* __restrict__ sdst, float* __restrict__ ssum,
                          unsigned* __restrict__ menc){
    int lane = threadIdx.x & 63;
    int row = blockIdx.x*4 + (threadIdx.x >> 6);
    const float* hp = hW + (size_t)row*128;
    float h0 = hp[lane], h1 = hp[lane+64];
    float d0 = h0*as_[lane] + h1*as_[lane+64];
    float d1 = h0*ad_[lane] + h1*ad_[lane+64];
    #pragma unroll
    for(int off=32; off; off>>=1){
        d0 += __shfl_xor(d0, off);
        d1 += __shfl_xor(d1, off);
    }
    if(lane==0){
        ssrc[row] = d0; sdst[row] = d1;
        ssum[row] = 0.f; menc[row] = 0u;   // 0 < enc_f(any finite v)
    }
}

// ---------------- edge pass 1 ----------------
__global__ void k_edge1(const int* __restrict__ src, const int* __restrict__ dst,
                        const float* __restrict__ ssrc, const float* __restrict__ sdst,
                        float* __restrict__ ebuf, unsigned* __restrict__ menc){
    int e = blockIdx.x*256 + threadIdx.x;   // e < NE_+NN_
    int s, d;
    if(e < NE_){ s = src[e]; d = dst[e]; } else { s = d = e - NE_; }
    float v = ssrc[s] + sdst[d];
    v = (v > 0.f) ? v : 0.2f*v;
    ebuf[e] = v;
    atomicMax(&menc[d], enc_f(v));
}

// ---------------- edge pass 2 ----------------
__global__ void k_edge2(const int* __restrict__ dst, const unsigned* __restrict__ menc,
                        float* __restrict__ ebuf, float* __restrict__ ssum){
    int e = blockIdx.x*256 + threadIdx.x;
    int d = (e < NE_) ? dst[e] : (e - NE_);
    float m = dec_f(menc[d]);
    float ex = __expf(ebuf[e] - m);
    ebuf[e] = ex;
    atomicAdd(&ssum[d], ex);
}

// ---------------- edge pass 3 (LDS-staged per graph) + alpha + bias + gelu ----
// grid (32 graphs, 16 ch-groups of 8); block 256. agg[2048][8] = 64KB LDS.
__global__ void __launch_bounds__(256) k_edge3_lds(
        const int* __restrict__ src, const int* __restrict__ dst,
        const float* __restrict__ ebuf, const float* __restrict__ ssum,
        const float* __restrict__ hW, const float* __restrict__ bias,
        float* __restrict__ hAgg){
    __shared__ float agg[2048][8];
    int g  = blockIdx.x;
    int c0 = blockIdx.y << 3;
    int t  = threadIdx.x;
    int cc = t & 7;
    int elane = t >> 3;              // 0..31 (32 edges per iter)

    for(int idx = t; idx < 2048*8; idx += 256)
        ((float*)agg)[idx] = 0.f;
    __syncthreads();

    const int gbase_e = g << 12;     // g*4096 edges
    const int gbase_n = g << 11;     // g*2048 nodes
    for(int i = 0; i < 192; i++){
        int eg = i*32 + elane;       // 0..6143
        int s, dloc; float a;
        if(eg < 4096){
            int e = gbase_e + eg;
            s    = src[e];
            int d = dst[e];
            dloc = d - gbase_n;
            a    = ebuf[e] / ssum[d];
        } else {
            int nl = eg - 4096;
            s    = gbase_n + nl;
            dloc = nl;
            a    = ebuf[NE_ + gbase_n + nl] / ssum[gbase_n + nl];
        }
        float v = hW[(size_t)s*128 + c0 + cc] * a;
        atomicAdd(&agg[dloc][cc], v);
    }
    __syncthreads();

    for(int idx = t; idx < 2048*8; idx += 256){
        int nl = idx >> 3;
        int ch = c0 + (idx & 7);
        hAgg[((size_t)(gbase_n + nl))*128 + ch] = gelu_f(agg[nl][idx & 7] + bias[ch]);
    }
}

// ------- fused edge-FC + GRU input projection -------
__global__ void k_ef_x3(const float* __restrict__ h3, const int* __restrict__ src,
                        const int* __restrict__ dst, const float* __restrict__ fcW,
                        const float* __restrict__ fcb,
                        const float* __restrict__ Wz, const float* __restrict__ Wr,
                        const float* __restrict__ Wh, const float* __restrict__ bz,
                        const float* __restrict__ br, const float* __restrict__ bh,
                        float* __restrict__ X3){
    __shared__ float efs[16][128];
    int lane = threadIdx.x & 63;
    int wy = threadIdx.x >> 6;
    int e0 = blockIdx.x*16 + wy*4;

    {
        float acc0[4] = {0,0,0,0}, acc1[4] = {0,0,0,0};
        #pragma unroll
        for(int half=0; half<2; half++){
            const float* rowp[4];
            #pragma unroll
            for(int i=0;i<4;i++){
                int n = (half==0) ? src[e0+i] : dst[e0+i];
                rowp[i] = h3 + (size_t)n*128;
            }
            #pragma unroll 2
            for(int k=0;k<128;k+=4){
                float4 av[4];
                #pragma unroll
                for(int i=0;i<4;i++) av[i] = *(const float4*)(rowp[i] + k);
                #pragma unroll
                for(int kk=0;kk<4;kk++){
                    int kw = half*128 + k + kk;
                    float w0 = fcW[(size_t)kw*128 + lane];
                    float w1 = fcW[(size_t)kw*128 + 64 + lane];
                    #pragma unroll
                    for(int i=0;i<4;i++){
                        float a = ((const float*)&av[i])[kk];
                        acc0[i] += a*w0;
                        acc1[i] += a*w1;
                    }
                }
            }
        }
        float b0 = fcb[lane], b1 = fcb[64+lane];
        #pragma unroll
        for(int i=0;i<4;i++){
            efs[wy*4+i][lane]      = gelu_f(acc0[i] + b0);
            efs[wy*4+i][64 + lane] = gelu_f(acc1[i] + b1);
        }
    }
    __syncthreads();
    {
        float accz[4] = {0,0,0,0}, accr[4] = {0,0,0,0}, acch[4] = {0,0,0,0};
        #pragma unroll 2
        for(int k=0;k<128;k+=4){
            #pragma unroll
            for(int kk=0;kk<4;kk++){
                float w0 = Wz[(size_t)(k+kk)*64 + lane];
                float w1 = Wr[(size_t)(k+kk)*64 + lane];
                float w2 = Wh[(size_t)(k+kk)*64 + lane];
                #pragma unroll
                for(int i=0;i<4;i++){
                    float a = efs[wy*4+i][k+kk];
                    accz[i] += a*w0;
                    accr[i] += a*w1;
                    acch[i] += a*w2;
                }
            }
        }
        float b0 = bz[lane], b1 = br[lane], b2 = bh[lane];
        #pragma unroll
        for(int i=0;i<4;i++){
            int e = e0 + i;
            int bb = e >> 12;
            int t  = e & 4095;
            float* o = X3 + ((size_t)t*32 + bb)*192;
            o[lane]       = accz[i] + b0;
            o[64 + lane]  = accr[i] + b1;
            o[128 + lane] = acch[i] + b2;
        }
    }
}

// ---------------- GRU: 2 waves/batch, ONE exchange per step -------------------
// wave0 owns the z-gate matvec, wave1 the r-gate; BOTH redundantly compute the
// Wh matvec (so only one barrier/step). Broadcast packs (h, rh) come from
// uniform-address ds_read_b128 of f16 vectors (LDS broadcast) instead of
// readlane chains. h stays f32-replicated in both waves. Ring prefetch as R11.
__global__ void __launch_bounds__(128) k_gru(const float* __restrict__ X3,
                       const float* __restrict__ Wz, const float* __restrict__ Wr,
                       const float* __restrict__ Wh, float* __restrict__ out){
    __shared__ float  ring[D_][192];
    __shared__ float  Zs[2][64];
    __shared__ __align__(16) unsigned short RHs[2][64];
    __shared__ __align__(16) unsigned short Hs[2][64];
    int b = blockIdx.x;
    int j = threadIdx.x & 63;
    int w = __builtin_amdgcn_readfirstlane(threadIdx.x >> 6);  // 0..1

    // own gate weights + Wh weights, f16x2-packed over k-pairs
    const float* Wg = (w == 0) ? Wz : Wr;
    f16x2 wgp[32], whp[32];
    #pragma unroll
    for(int i=0;i<32;i++){
        int r0 = 128 + 2*i;
        wgp[i] = __builtin_amdgcn_cvt_pkrtz(Wg[(size_t)r0*64 + j], Wg[(size_t)(r0+1)*64 + j]);
        whp[i] = __builtin_amdgcn_cvt_pkrtz(Wh[(size_t)r0*64 + j], Wh[(size_t)(r0+1)*64 + j]);
    }

    Hs[w][j] = 0;                      // h=0 in f16, own slot (in-wave use only)

    // prologue: wave 0 fills ring slots 0..D-1 (3 loads per slot)
    if(w == 0){
        for(int s=0;s<D_;s++){
            const float* gp = X3 + ((size_t)s*32 + b)*192 + j;
            gload_lds4(gp,       &ring[s][0],   j);
            gload_lds4(gp + 64,  &ring[s][64],  j);
            gload_lds4(gp + 128, &ring[s][128], j);
        }
        asm volatile("s_waitcnt vmcnt(21)" ::: "memory");   // slot 0 ready
        __builtin_amdgcn_sched_barrier(0);
    }
    asm volatile("s_waitcnt lgkmcnt(0)" ::: "memory");      // Hs init done
    __builtin_amdgcn_s_barrier();

    float h = 0.f;
    const int gate_off = w << 6;       // wave0: z row, wave1: r row
    for(int step=0; step<T_; step++){
        int sl = step & (D_-1);
        int p  = step & 1;
        float xg = ring[sl][gate_off + j];
        float xh = ring[sl][128 + j];

        // phase 1: own-gate full matvec; h-packs via uniform ds_read_b128
        const uint4* hp4 = (const uint4*)&Hs[w][0];
        float a0 = xg, a1 = 0.f, a2 = 0.f, a3 = 0.f;
        #pragma unroll
        for(int m=0;m<8;m++){
            uint4 u = hp4[m];
            a0 = dot2(i2h((int)u.x), wgp[4*m],   a0);
            a1 = dot2(i2h((int)u.y), wgp[4*m+1], a1);
            a2 = dot2(i2h((int)u.z), wgp[4*m+2], a2);
            a3 = dot2(i2h((int)u.w), wgp[4*m+3], a3);
        }
        float sg = (a0+a1)+(a2+a3);
        float g  = __builtin_amdgcn_rcpf(1.f + __expf(-sg));  // z_j (w0) / r_j (w1)
        if(w == 0){
            Zs[p][j] = g;
        } else {
            float rh = g * h;
            RHs[p][j] = (unsigned short)(h2i(__builtin_amdgcn_cvt_pkrtz(rh, rh)) & 0xffff);
        }
        if(w == 0){
            asm volatile("s_waitcnt vmcnt(18)" ::: "memory"); // next step's slot ready
        }
        asm volatile("s_waitcnt lgkmcnt(0)" ::: "memory");    // Zs/RHs visible
        __builtin_amdgcn_s_barrier();                         // the ONE barrier

        // slot sl now free: wave 0 prefetches step+D into it
        if(w == 0){
            int ps = (step + D_ < T_) ? (step + D_) : (T_-1);
            const float* gp = X3 + ((size_t)ps*32 + b)*192 + j;
            gload_lds4(gp,       &ring[sl][0],   j);
            gload_lds4(gp + 64,  &ring[sl][64],  j);
            gload_lds4(gp + 128, &ring[sl][128], j);
        }

        // phase 2: full Wh matvec (redundant in both waves) from RH packs
        const uint4* rp4 = (const uint4*)&RHs[p][0];
        float c0 = xh, c1 = 0.f, c2 = 0.f, c3 = 0.f;
        #pragma unroll
        for(int m=0;m<8;m++){
            uint4 u = rp4[m];
            c0 = dot2(i2h((int)u.x), whp[4*m],   c0);
            c1 = dot2(i2h((int)u.y), whp[4*m+1], c1);
            c2 = dot2(i2h((int)u.z), whp[4*m+2], c2);
            c3 = dot2(i2h((int)u.w), whp[4*m+3], c3);
        }
        float s2 = (c0+c1)+(c2+c3);
        float ht = fmaxf(s2, 0.01f*s2);
        float z  = (w == 0) ? g : Zs[p][j];
        h = fmaf(z, ht - h, h);                 // replicated update
        Hs[w][j] = (unsigned short)(h2i(__builtin_amdgcn_cvt_pkrtz(h, h)) & 0xffff);
    }
    if(w == 0) out[(size_t)b*64 + j] = h;
}

extern "C" void kernel_launch(void* const* d_in, const int* in_sizes, int n_in,
                              void* d_out, int out_size, void* d_ws, size_t ws_size,
                              hipStream_t stream) {
    const float* x    = (const float*)d_in[0];
    const int*   nidx = (const int*)d_in[1];
    const int*   src  = (const int*)d_in[2];
    const int*   dst  = src + NE_;
    const float* emb  = (const float*)d_in[3];
    const float* W1 = (const float*)d_in[4];
    const float* a1s = (const float*)d_in[5];
    const float* a1d = (const float*)d_in[6];
    const float* b1 = (const float*)d_in[7];
    const float* W2 = (const float*)d_in[8];
    const float* a2s = (const float*)d_in[9];
    const float* a2d = (const float*)d_in[10];
    const float* b2 = (const float*)d_in[11];
    const float* W3 = (const float*)d_in[12];
    const float* a3s = (const float*)d_in[13];
    const float* a3d = (const float*)d_in[14];
    const float* b3 = (const float*)d_in[15];
    const float* fcW = (const float*)d_in[16];
    const float* fcb = (const float*)d_in[17];
    const float* Wz = (const float*)d_in[18];
    const float* bz = (const float*)d_in[19];
    const float* Wr = (const float*)d_in[20];
    const float* br = (const float*)d_in[21];
    const float* Wh = (const float*)d_in[22];
    const float* bh = (const float*)d_in[23];
    float* out = (float*)d_out;

    float* ws = (float*)d_ws;
    float* hAgg = ws;                          // NN*128
    float* X3   = hAgg + (size_t)NN_*128;      // NE*192
    float* bufA = X3;                          // NN*128   (alias)
    float* h64  = bufA + (size_t)NN_*128;      // NN*64    (alias)
    float* ssrc = h64  + (size_t)NN_*64;       // NN       (alias)
    float* sdst = ssrc + NN_;                  // NN
    float* ssum = sdst + NN_;                  // NN
    unsigned* menc = (unsigned*)(ssum + NN_);  // NN
    float* ebuf = (float*)menc + NN_;          // NE+NN

    const int EP = NE_ + NN_;

    k_embed<<<NN_*64/256, 256, 0, stream>>>(x, nidx, emb, h64);

    const float* Ws[3]  = {W1, W2, W3};
    const float* as_[3] = {a1s, a2s, a3s};
    const float* ad_[3] = {a1d, a2d, a3d};
    const float* bs[3]  = {b1, b2, b3};

    for(int l=0; l<3; l++){
        if(l == 0)
            k_gemm_node<64><<<NN_/16, 256, 0, stream>>>(h64, Ws[l], bufA);
        else
            k_gemm_node<128><<<NN_/16, 256, 0, stream>>>(hAgg, Ws[l], bufA);
        k_rowdots<<<NN_/4, 256, 0, stream>>>(bufA, as_[l], ad_[l], ssrc, sdst, ssum, menc);
        k_edge1<<<EP/256, 256, 0, stream>>>(src, dst, ssrc, sdst, ebuf, menc);
        k_edge2<<<EP/256, 256, 0, stream>>>(dst, menc, ebuf, ssum);
        k_edge3_lds<<<dim3(B_, 16), 256, 0, stream>>>(src, dst, ebuf, ssum, bufA, bs[l], hAgg);
    }

    k_ef_x3<<<NE_/16, 256, 0, stream>>>(hAgg, src, dst, fcW, fcb,
                                        Wz, Wr, Wh, bz, br, bh, X3);
    k_gru<<<B_, 128, 0, stream>>>(X3, Wz, Wr, Wh, out);
}

// Round 14
// 3289.775 us; speedup vs baseline: 1.1941x; 1.0350x over previous
//
#include <hip/hip_runtime.h>
#include <hip/hip_bf16.h>
#include <math.h>

#define NN_ 65536
#define NE_ 131072
#define B_  32
#define T_  4096
#define D_  8          // GRU X3 ring-prefetch depth (steps)

typedef __fp16 f16x2 __attribute__((ext_vector_type(2)));
typedef unsigned int u32;

__device__ __forceinline__ float gelu_f(float x){
    return 0.5f*x*(1.0f + erff(x*0.70710678118654752f));
}

__device__ __forceinline__ unsigned enc_f(float f){
    unsigned b = __float_as_uint(f);
    return (b & 0x80000000u) ? ~b : (b | 0x80000000u);
}
__device__ __forceinline__ float dec_f(unsigned u){
    return (u & 0x80000000u) ? __uint_as_float(u ^ 0x80000000u) : __uint_as_float(~u);
}

__device__ __forceinline__ int h2i(f16x2 h){ union{int i; f16x2 h;} u; u.h=h; return u.i; }
__device__ __forceinline__ f16x2 i2h(int i){ union{int i; f16x2 h;} u; u.i=i; return u.h; }

__device__ __forceinline__ float dot2(f16x2 a, f16x2 b, float c){
#if __has_builtin(__builtin_amdgcn_fdot2)
    return __builtin_amdgcn_fdot2(a, b, c, false);
#else
    return c + (float)a.x*(float)b.x + (float)a.y*(float)b.y;
#endif
}

// async global->LDS: lane i loads *(g_perlane) -> lds_base + i*4
__device__ __forceinline__ void gload_lds4(const float* g, float* l, int lane){
#if __has_builtin(__builtin_amdgcn_global_load_lds)
    __builtin_amdgcn_global_load_lds((const __attribute__((address_space(1))) u32*)g,
                                     (__attribute__((address_space(3))) u32*)l, 4, 0, 0);
#else
    l[lane] = *g;
#endif
}

// ---------------- embed concat ----------------
__global__ void k_embed(const float* __restrict__ x, const int* __restrict__ nidx,
                        const float* __restrict__ emb, float* __restrict__ h64){
    int gid = blockIdx.x*256 + threadIdx.x;
    int n = gid >> 6, c = gid & 63;
    float v = (c < 32) ? x[(size_t)n*32 + c] : emb[(size_t)nidx[n]*32 + (c-32)];
    h64[gid] = v;
}

// ---------------- node GEMM: C[M,128] = A[M,K] @ W[K,128] ----------------
template<int K>
__global__ void k_gemm_node(const float* __restrict__ A, const float* __restrict__ W,
                            float* __restrict__ C){
    int lane = threadIdx.x & 63;
    int wy = threadIdx.x >> 6;
    int r0 = blockIdx.x*16 + wy*4;
    const float* a0 = A + (size_t)r0*K;
    float acc0[4] = {0,0,0,0}, acc1[4] = {0,0,0,0};
    #pragma unroll 4
    for(int k=0;k<K;k+=4){
        float4 av[4];
        #pragma unroll
        for(int i=0;i<4;i++) av[i] = *(const float4*)(a0 + (size_t)i*K + k);
        #pragma unroll
        for(int kk=0;kk<4;kk++){
            float w0 = W[(size_t)(k+kk)*128 + lane];
            float w1 = W[(size_t)(k+kk)*128 + 64 + lane];
            #pragma unroll
            for(int i=0;i<4;i++){
                float a = ((const float*)&av[i])[kk];
                acc0[i] += a*w0;
                acc1[i] += a*w1;
            }
        }
    }
    #pragma unroll
    for(int i=0;i<4;i++){
        C[(size_t)(r0+i)*128 + lane]      = acc0[i];
        C[(size_t)(r0+i)*128 + 64 + lane] = acc1[i];
    }
}

// ---------------- per-row dots (+ zero-init of ssum/menc) ---------------------
__global__ void k_rowdots(const float* __restrict__ hW, const float* __restrict__ as_,
                          const float* __restrict__ ad_, float* __restrict__ ssrc,
                          float* __restrict__ sdst, float* __restrict__ ssum,
                          unsigned* __restrict__ menc){
    int lane = threadIdx.x & 63;
    int row = blockIdx.x*4 + (threadIdx.x >> 6);
    const float* hp = hW + (size_t)row*128;
    float h0 = hp[lane], h1 = hp[lane+64];
    float d0 = h0*as_[lane] + h1*as_[lane+64];
    float d1 = h0*ad_[lane] + h1*ad_[lane+64];
    #pragma unroll
    for(int off=32; off; off>>=1){
        d0 += __shfl_xor(d0, off);
        d1 += __shfl_xor(d1, off);
    }
    if(lane==0){
        ssrc[row] = d0; sdst[row] = d1;
        ssum[row] = 0.f; menc[row] = 0u;   // 0 < enc_f(any finite v)
    }
}

// ---------------- edge pass 1 ----------------
__global__ void k_edge1(const int* __restrict__ src, const int* __restrict__ dst,
                        const float* __restrict__ ssrc, const float* __restrict__ sdst,
                        float* __restrict__ ebuf, unsigned* __restrict__ menc){
    int e = blockIdx.x*256 + threadIdx.x;   // e < NE_+NN_
    int s, d;
    if(e < NE_){ s = src[e]; d = dst[e]; } else { s = d = e - NE_; }
    float v = ssrc[s] + sdst[d];
    v = (v > 0.f) ? v : 0.2f*v;
    ebuf[e] = v;
    atomicMax(&menc[d], enc_f(v));
}

// ---------------- edge pass 2 ----------------
__global__ void k_edge2(const int* __restrict__ dst, const unsigned* __restrict__ menc,
                        float* __restrict__ ebuf, float* __restrict__ ssum){
    int e = blockIdx.x*256 + threadIdx.x;
    int d = (e < NE_) ? dst[e] : (e - NE_);
    float m = dec_f(menc[d]);
    float ex = __expf(ebuf[e] - m);
    ebuf[e] = ex;
    atomicAdd(&ssum[d], ex);
}

// ---------------- edge pass 3 (LDS-staged per graph) + alpha + bias + gelu ----
// grid (32 graphs, 16 ch-groups of 8); block 256. agg[2048][8] = 64KB LDS.
__global__ void __launch_bounds__(256) k_edge3_lds(
        const int* __restrict__ src, const int* __restrict__ dst,
        const float* __restrict__ ebuf, const float* __restrict__ ssum,
        const float* __restrict__ hW, const float* __restrict__ bias,
        float* __restrict__ hAgg){
    __shared__ float agg[2048][8];
    int g  = blockIdx.x;
    int c0 = blockIdx.y << 3;
    int t  = threadIdx.x;
    int cc = t & 7;
    int elane = t >> 3;              // 0..31 (32 edges per iter)

    for(int idx = t; idx < 2048*8; idx += 256)
        ((float*)agg)[idx] = 0.f;
    __syncthreads();

    const int gbase_e = g << 12;     // g*4096 edges
    const int gbase_n = g << 11;     // g*2048 nodes
    for(int i = 0; i < 192; i++){
        int eg = i*32 + elane;       // 0..6143
        int s, dloc; float a;
        if(eg < 4096){
            int e = gbase_e + eg;
            s    = src[e];
            int d = dst[e];
            dloc = d - gbase_n;
            a    = ebuf[e] / ssum[d];
        } else {
            int nl = eg - 4096;
            s    = gbase_n + nl;
            dloc = nl;
            a    = ebuf[NE_ + gbase_n + nl] / ssum[gbase_n + nl];
        }
        float v = hW[(size_t)s*128 + c0 + cc] * a;
        atomicAdd(&agg[dloc][cc], v);
    }
    __syncthreads();

    for(int idx = t; idx < 2048*8; idx += 256){
        int nl = idx >> 3;
        int ch = c0 + (idx & 7);
        hAgg[((size_t)(gbase_n + nl))*128 + ch] = gelu_f(agg[nl][idx & 7] + bias[ch]);
    }
}

// ------- fused edge-FC + GRU input projection -------
__global__ void k_ef_x3(const float* __restrict__ h3, const int* __restrict__ src,
                        const int* __restrict__ dst, const float* __restrict__ fcW,
                        const float* __restrict__ fcb,
                        const float* __restrict__ Wz, const float* __restrict__ Wr,
                        const float* __restrict__ Wh, const float* __restrict__ bz,
                        const float* __restrict__ br, const float* __restrict__ bh,
                        float* __restrict__ X3){
    __shared__ float efs[16][128];
    int lane = threadIdx.x & 63;
    int wy = threadIdx.x >> 6;
    int e0 = blockIdx.x*16 + wy*4;

    {
        float acc0[4] = {0,0,0,0}, acc1[4] = {0,0,0,0};
        #pragma unroll
        for(int half=0; half<2; half++){
            const float* rowp[4];
            #pragma unroll
            for(int i=0;i<4;i++){
                int n = (half==0) ? src[e0+i] : dst[e0+i];
                rowp[i] = h3 + (size_t)n*128;
            }
            #pragma unroll 2
            for(int k=0;k<128;k+=4){
                float4 av[4];
                #pragma unroll
                for(int i=0;i<4;i++) av[i] = *(const float4*)(rowp[i] + k);
                #pragma unroll
                for(int kk=0;kk<4;kk++){
                    int kw = half*128 + k + kk;
                    float w0 = fcW[(size_t)kw*128 + lane];
                    float w1 = fcW[(size_t)kw*128 + 64 + lane];
                    #pragma unroll
                    for(int i=0;i<4;i++){
                        float a = ((const float*)&av[i])[kk];
                        acc0[i] += a*w0;
                        acc1[i] += a*w1;
                    }
                }
            }
        }
        float b0 = fcb[lane], b1 = fcb[64+lane];
        #pragma unroll
        for(int i=0;i<4;i++){
            efs[wy*4+i][lane]      = gelu_f(acc0[i] + b0);
            efs[wy*4+i][64 + lane] = gelu_f(acc1[i] + b1);
        }
    }
    __syncthreads();
    {
        float accz[4] = {0,0,0,0}, accr[4] = {0,0,0,0}, acch[4] = {0,0,0,0};
        #pragma unroll 2
        for(int k=0;k<128;k+=4){
            #pragma unroll
            for(int kk=0;kk<4;kk++){
                float w0 = Wz[(size_t)(k+kk)*64 + lane];
                float w1 = Wr[(size_t)(k+kk)*64 + lane];
                float w2 = Wh[(size_t)(k+kk)*64 + lane];
                #pragma unroll
                for(int i=0;i<4;i++){
                    float a = efs[wy*4+i][k+kk];
                    accz[i] += a*w0;
                    accr[i] += a*w1;
                    acch[i] += a*w2;
                }
            }
        }
        float b0 = bz[lane], b1 = br[lane], b2 = bh[lane];
        #pragma unroll
        for(int i=0;i<4;i++){
            int e = e0 + i;
            int bb = e >> 12;
            int t  = e & 4095;
            float* o = X3 + ((size_t)t*32 + bb)*192;
            o[lane]       = accz[i] + b0;
            o[64 + lane]  = accr[i] + b1;
            o[128 + lane] = acch[i] + b2;
        }
    }
}

// ---------------- GRU: 2 waves/batch, one exchange/step, latency-hoisted ------
// R12 structure + two RAW-latency fixes: (1) next-step xg/xh prefetched during
// phase 2 (slot sl+1 resident for D-1 steps); (2) h-pack reads split: hu[0..3]
// issued right after the Hs write (same-wave in-order DS), hu[4..7] at phase-1
// top where latency hides under the first 16 dot2s.
__global__ void __launch_bounds__(128) k_gru(const float* __restrict__ X3,
                       const float* __restrict__ Wz, const float* __restrict__ Wr,
                       const float* __restrict__ Wh, float* __restrict__ out){
    __shared__ float  ring[D_][192];
    __shared__ float  Zs[2][64];
    __shared__ __align__(16) unsigned short RHs[2][64];
    __shared__ __align__(16) unsigned short Hs[2][64];
    int b = blockIdx.x;
    int j = threadIdx.x & 63;
    int w = __builtin_amdgcn_readfirstlane(threadIdx.x >> 6);  // 0..1

    // own gate weights + Wh weights, f16x2-packed over k-pairs
    const float* Wg = (w == 0) ? Wz : Wr;
    f16x2 wgp[32], whp[32];
    #pragma unroll
    for(int i=0;i<32;i++){
        int r0 = 128 + 2*i;
        wgp[i] = __builtin_amdgcn_cvt_pkrtz(Wg[(size_t)r0*64 + j], Wg[(size_t)(r0+1)*64 + j]);
        whp[i] = __builtin_amdgcn_cvt_pkrtz(Wh[(size_t)r0*64 + j], Wh[(size_t)(r0+1)*64 + j]);
    }

    Hs[w][j] = 0;                      // h=0 in f16, own slot (in-wave use only)

    // prologue: wave 0 fills ring slots 0..D-1 (3 loads per slot)
    if(w == 0){
        for(int s=0;s<D_;s++){
            const float* gp = X3 + ((size_t)s*32 + b)*192 + j;
            gload_lds4(gp,       &ring[s][0],   j);
            gload_lds4(gp + 64,  &ring[s][64],  j);
            gload_lds4(gp + 128, &ring[s][128], j);
        }
        asm volatile("s_waitcnt vmcnt(21)" ::: "memory");   // slot 0 ready
        __builtin_amdgcn_sched_barrier(0);
    }
    asm volatile("s_waitcnt lgkmcnt(0)" ::: "memory");      // Hs init done
    __builtin_amdgcn_s_barrier();

    float h = 0.f;
    const int gate_off = w << 6;       // wave0: z row, wave1: r row
    const uint4* hp4 = (const uint4*)&Hs[w][0];

    // initial x + front-half h-packs
    float xg = ring[0][gate_off + j];
    float xh = ring[0][128 + j];
    uint4 hu0 = hp4[0], hu1 = hp4[1], hu2 = hp4[2], hu3 = hp4[3];

    for(int step=0; step<T_; step++){
        int sl  = step & (D_-1);
        int sl1 = (step+1) & (D_-1);
        int p   = step & 1;

        // back-half h-packs: latency hides under the first 16 dot2s
        uint4 hu4 = hp4[4], hu5 = hp4[5], hu6 = hp4[6], hu7 = hp4[7];

        // phase 1: own-gate full matvec
        float a0 = xg, a1 = 0.f, a2 = 0.f, a3 = 0.f;
        a0 = dot2(i2h((int)hu0.x), wgp[0],  a0);
        a1 = dot2(i2h((int)hu0.y), wgp[1],  a1);
        a2 = dot2(i2h((int)hu0.z), wgp[2],  a2);
        a3 = dot2(i2h((int)hu0.w), wgp[3],  a3);
        a0 = dot2(i2h((int)hu1.x), wgp[4],  a0);
        a1 = dot2(i2h((int)hu1.y), wgp[5],  a1);
        a2 = dot2(i2h((int)hu1.z), wgp[6],  a2);
        a3 = dot2(i2h((int)hu1.w), wgp[7],  a3);
        a0 = dot2(i2h((int)hu2.x), wgp[8],  a0);
        a1 = dot2(i2h((int)hu2.y), wgp[9],  a1);
        a2 = dot2(i2h((int)hu2.z), wgp[10], a2);
        a3 = dot2(i2h((int)hu2.w), wgp[11], a3);
        a0 = dot2(i2h((int)hu3.x), wgp[12], a0);
        a1 = dot2(i2h((int)hu3.y), wgp[13], a1);
        a2 = dot2(i2h((int)hu3.z), wgp[14], a2);
        a3 = dot2(i2h((int)hu3.w), wgp[15], a3);
        a0 = dot2(i2h((int)hu4.x), wgp[16], a0);
        a1 = dot2(i2h((int)hu4.y), wgp[17], a1);
        a2 = dot2(i2h((int)hu4.z), wgp[18], a2);
        a3 = dot2(i2h((int)hu4.w), wgp[19], a3);
        a0 = dot2(i2h((int)hu5.x), wgp[20], a0);
        a1 = dot2(i2h((int)hu5.y), wgp[21], a1);
        a2 = dot2(i2h((int)hu5.z), wgp[22], a2);
        a3 = dot2(i2h((int)hu5.w), wgp[23], a3);
        a0 = dot2(i2h((int)hu6.x), wgp[24], a0);
        a1 = dot2(i2h((int)hu6.y), wgp[25], a1);
        a2 = dot2(i2h((int)hu6.z), wgp[26], a2);
        a3 = dot2(i2h((int)hu6.w), wgp[27], a3);
        a0 = dot2(i2h((int)hu7.x), wgp[28], a0);
        a1 = dot2(i2h((int)hu7.y), wgp[29], a1);
        a2 = dot2(i2h((int)hu7.z), wgp[30], a2);
        a3 = dot2(i2h((int)hu7.w), wgp[31], a3);
        float sg = (a0+a1)+(a2+a3);
        float g  = __builtin_amdgcn_rcpf(1.f + __expf(-sg));  // z_j (w0) / r_j (w1)
        if(w == 0){
            Zs[p][j] = g;
        } else {
            float rh = g * h;
            RHs[p][j] = (unsigned short)(h2i(__builtin_amdgcn_cvt_pkrtz(rh, rh)) & 0xffff);
        }
        if(w == 0){
            asm volatile("s_waitcnt vmcnt(18)" ::: "memory"); // next step's slot ready
        }
        asm volatile("s_waitcnt lgkmcnt(0)" ::: "memory");    // Zs/RHs visible
        __builtin_amdgcn_s_barrier();                         // the ONE barrier

        // slot sl now free: wave 0 prefetches step+D into it
        if(w == 0){
            int ps = (step + D_ < T_) ? (step + D_) : (T_-1);
            const float* gp = X3 + ((size_t)ps*32 + b)*192 + j;
            gload_lds4(gp,       &ring[sl][0],   j);
            gload_lds4(gp + 64,  &ring[sl][64],  j);
            gload_lds4(gp + 128, &ring[sl][128], j);
        }

        // prefetch next step's x during phase 2 (slot sl1 is resident)
        float nxg = ring[sl1][gate_off + j];
        float nxh = ring[sl1][128 + j];

        // phase 2: full Wh matvec (redundant in both waves) from RH packs
        const uint4* rp4 = (const uint4*)&RHs[p][0];
        float c0 = xh, c1 = 0.f, c2 = 0.f, c3 = 0.f;
        #pragma unroll
        for(int m=0;m<8;m++){
            uint4 u = rp4[m];
            c0 = dot2(i2h((int)u.x), whp[4*m],   c0);
            c1 = dot2(i2h((int)u.y), whp[4*m+1], c1);
            c2 = dot2(i2h((int)u.z), whp[4*m+2], c2);
            c3 = dot2(i2h((int)u.w), whp[4*m+3], c3);
        }
        float s2 = (c0+c1)+(c2+c3);
        float ht = fmaxf(s2, 0.01f*s2);
        float z  = (w == 0) ? g : Zs[p][j];
        h = fmaf(z, ht - h, h);                 // replicated update
        Hs[w][j] = (unsigned short)(h2i(__builtin_amdgcn_cvt_pkrtz(h, h)) & 0xffff);
        // early-issue front-half h-packs for next step (same-wave in-order DS)
        hu0 = hp4[0]; hu1 = hp4[1]; hu2 = hp4[2]; hu3 = hp4[3];
        xg = nxg; xh = nxh;
    }
    if(w == 0) out[(size_t)b*64 + j] = h;
}

extern "C" void kernel_launch(void* const* d_in, const int* in_sizes, int n_in,
                              void* d_out, int out_size, void* d_ws, size_t ws_size,
                              hipStream_t stream) {
    const float* x    = (const float*)d_in[0];
    const int*   nidx = (const int*)d_in[1];
    const int*   src  = (const int*)d_in[2];
    const int*   dst  = src + NE_;
    const float* emb  = (const float*)d_in[3];
    const float* W1 = (const float*)d_in[4];
    const float* a1s = (const float*)d_in[5];
    const float* a1d = (const float*)d_in[6];
    const float* b1 = (const float*)d_in[7];
    const float* W2 = (const float*)d_in[8];
    const float* a2s = (const float*)d_in[9];
    const float* a2d = (const float*)d_in[10];
    const float* b2 = (const float*)d_in[11];
    const float* W3 = (const float*)d_in[12];
    const float* a3s = (const float*)d_in[13];
    const float* a3d = (const float*)d_in[14];
    const float* b3 = (const float*)d_in[15];
    const float* fcW = (const float*)d_in[16];
    const float* fcb = (const float*)d_in[17];
    const float* Wz = (const float*)d_in[18];
    const float* bz = (const float*)d_in[19];
    const float* Wr = (const float*)d_in[20];
    const float* br = (const float*)d_in[21];
    const float* Wh = (const float*)d_in[22];
    const float* bh = (const float*)d_in[23];
    float* out = (float*)d_out;

    float* ws = (float*)d_ws;
    float* hAgg = ws;                          // NN*128
    float* X3   = hAgg + (size_t)NN_*128;      // NE*192
    float* bufA = X3;                          // NN*128   (alias)
    float* h64  = bufA + (size_t)NN_*128;      // NN*64    (alias)
    float* ssrc = h64  + (size_t)NN_*64;       // NN       (alias)
    float* sdst = ssrc + NN_;                  // NN
    float* ssum = sdst + NN_;                  // NN
    unsigned* menc = (unsigned*)(ssum + NN_);  // NN
    float* ebuf = (float*)menc + NN_;          // NE+NN

    const int EP = NE_ + NN_;

    k_embed<<<NN_*64/256, 256, 0, stream>>>(x, nidx, emb, h64);

    const float* Ws[3]  = {W1, W2, W3};
    const float* as_[3] = {a1s, a2s, a3s};
    const float* ad_[3] = {a1d, a2d, a3d};
    const float* bs[3]  = {b1, b2, b3};

    for(int l=0; l<3; l++){
        if(l == 0)
            k_gemm_node<64><<<NN_/16, 256, 0, stream>>>(h64, Ws[l], bufA);
        else
            k_gemm_node<128><<<NN_/16, 256, 0, stream>>>(hAgg, Ws[l], bufA);
        k_rowdots<<<NN_/4, 256, 0, stream>>>(bufA, as_[l], ad_[l], ssrc, sdst, ssum, menc);
        k_edge1<<<EP/256, 256, 0, stream>>>(src, dst, ssrc, sdst, ebuf, menc);
        k_edge2<<<EP/256, 256, 0, stream>>>(dst, menc, ebuf, ssum);
        k_edge3_lds<<<dim3(B_, 16), 256, 0, stream>>>(src, dst, ebuf, ssum, bufA, bs[l], hAgg);
    }

    k_ef_x3<<<NE_/16, 256, 0, stream>>>(hAgg, src, dst, fcW, fcb,
                                        Wz, Wr, Wh, bz, br, bh, X3);
    k_gru<<<B_, 128, 0, stream>>>(X3, Wz, Wr, Wh, out);
}